// Round 4
// baseline (244.864 us; speedup 1.0000x reference)
//
#include <hip/hip_runtime.h>

#define RN    8192
#define NSH   31          // shifts -15..15
#define BLK   1024        // threads per block (16 waves)
#define EPSF  1e-8f

// ---- AoS swizzle on float2-index: XOR bits 1..3 with bits 5..7. Bit 0
// untouched -> b128 (float4 = 2 adjacent float2) stays contiguous.
__device__ __forceinline__ int SWA(int i) { return i ^ (((i >> 5) & 7) << 1); }
__device__ __forceinline__ int SW4(int a) { return a ^ ((a >> 4) & 7); }  // float4-index view

// digit-reversed position of frequency k after DIF radices 8,8,8,16
__device__ __forceinline__ int PPOS(int k) {
  return ((k & 7) << 10) | (((k >> 3) & 7) << 7) | (((k >> 6) & 7) << 4) | (k >> 9);
}

// ---- DPP reductions (VALU pipe only; no LDS/bpermute traffic) ----
template<int CTRL, int RMASK>
__device__ __forceinline__ float dpp_add_f(float x) {
  int v = __builtin_amdgcn_update_dpp(0, __float_as_int(x), CTRL, RMASK, 0xf, true);
  return x + __int_as_float(v);
}
__device__ __forceinline__ float wave_sum63(float x) {   // total valid in lane 63
  x = dpp_add_f<0x111, 0xf>(x);   // row_shr:1
  x = dpp_add_f<0x112, 0xf>(x);   // row_shr:2
  x = dpp_add_f<0x114, 0xf>(x);   // row_shr:4
  x = dpp_add_f<0x118, 0xf>(x);   // row_shr:8
  x = dpp_add_f<0x142, 0xa>(x);   // row_bcast:15 -> rows 1,3
  x = dpp_add_f<0x143, 0xc>(x);   // row_bcast:31 -> rows 2,3
  return x;
}
__device__ __forceinline__ float row_sum15(float x) {    // 16-lane-group total in lane 15
  x = dpp_add_f<0x111, 0xf>(x);
  x = dpp_add_f<0x112, 0xf>(x);
  x = dpp_add_f<0x114, 0xf>(x);
  x = dpp_add_f<0x118, 0xf>(x);
  return x;
}

// ---- 8-point DFT in registers (forward) ----
__device__ __forceinline__ void dft8(float yr[8], float yi[8]) {
  const float C = 0.7071067811865476f;
  float ar, ai;
  float u0r = yr[0] + yr[4], u0i = yi[0] + yi[4];
  float v0r = yr[0] - yr[4], v0i = yi[0] - yi[4];
  float u1r = yr[1] + yr[5], u1i = yi[1] + yi[5];
  ar = yr[1] - yr[5]; ai = yi[1] - yi[5];
  float v1r = C * (ar + ai), v1i = C * (ai - ar);
  float u2r = yr[2] + yr[6], u2i = yi[2] + yi[6];
  ar = yr[2] - yr[6]; ai = yi[2] - yi[6];
  float v2r = ai, v2i = -ar;
  float u3r = yr[3] + yr[7], u3i = yi[3] + yi[7];
  ar = yr[3] - yr[7]; ai = yi[3] - yi[7];
  float v3r = C * (ai - ar), v3i = -C * (ar + ai);
  float t0r = u0r + u2r, t0i = u0i + u2i;
  float t1r = u1r + u3r, t1i = u1i + u3i;
  float t2r = u0r - u2r, t2i = u0i - u2i;
  float t3r = u1r - u3r, t3i = u1i - u3i;
  yr[0] = t0r + t1r; yi[0] = t0i + t1i;
  yr[4] = t0r - t1r; yi[4] = t0i - t1i;
  yr[2] = t2r + t3i; yi[2] = t2i - t3r;
  yr[6] = t2r - t3i; yi[6] = t2i + t3r;
  t0r = v0r + v2r; t0i = v0i + v2i;
  t1r = v1r + v3r; t1i = v1i + v3i;
  t2r = v0r - v2r; t2i = v0i - v2i;
  t3r = v1r - v3r; t3i = v1i - v3i;
  yr[1] = t0r + t1r; yi[1] = t0i + t1i;
  yr[5] = t0r - t1r; yi[5] = t0i - t1i;
  yr[3] = t2r + t3i; yi[3] = t2i - t3r;
  yr[7] = t2r - t3i; yi[7] = t2i + t3r;
}

__device__ __forceinline__ void dft16(float zr[16], float zi[16]) {
  float er[8], ei[8], odr[8], odi[8];
  #pragma unroll
  for (int m = 0; m < 8; ++m) {
    er[m] = zr[2*m];    ei[m] = zi[2*m];
    odr[m] = zr[2*m+1]; odi[m] = zi[2*m+1];
  }
  dft8(er, ei); dft8(odr, odi);
  const float c1 = 0.9238795325112867f, s1 = 0.3826834323650898f;
  const float C  = 0.7071067811865476f;
  const float WR[8] = {1.f,  c1,  C,  s1, 0.f, -s1, -C, -c1};
  const float WI[8] = {0.f, -s1, -C, -c1, -1.f, -c1, -C, -s1};
  #pragma unroll
  for (int q = 0; q < 8; ++q) {
    float tr = odr[q]*WR[q] - odi[q]*WI[q];
    float ti = odr[q]*WI[q] + odi[q]*WR[q];
    zr[q]     = er[q] + tr; zi[q]     = ei[q] + ti;
    zr[q + 8] = er[q] - tr; zi[q + 8] = ei[q] - ti;
  }
}

// one DIF radix-8 pass, 1 butterfly per thread, AoS float2 + swizzle
template<int LOG2S>
__device__ __forceinline__ void fft_pass8(float2* z, int t) {
  const int S = 1 << LOG2S;
  const int j = t & (S - 1);
  const int base = ((t >> LOG2S) << (LOG2S + 3)) + j;
  float ar[8], ai[8];
  #pragma unroll
  for (int m = 0; m < 8; ++m) {
    float2 v = z[SWA(base + m * S)];
    ar[m] = v.x; ai[m] = v.y;
  }
  dft8(ar, ai);
  const float angu = -3.14159265358979323846f / (4.0f * (float)S);
  float sn, cs;
  __sincosf(angu * (float)j, &sn, &cs);
  float wr = cs, wi = sn;
  #pragma unroll
  for (int q = 1; q < 8; ++q) {
    float tr = ar[q]*wr - ai[q]*wi;
    ai[q] = ar[q]*wi + ai[q]*wr; ar[q] = tr;
    if (q < 7) { float nr = wr*cs - wi*sn; wi = wr*sn + wi*cs; wr = nr; }
  }
  #pragma unroll
  for (int m = 0; m < 8; ++m) z[SWA(base + m * S)] = make_float2(ar[m], ai[m]);
}

__global__ __launch_bounds__(BLK, 8) void hybrid_row_kernel(
    const float* __restrict__ preds, const float* __restrict__ targets,
    float* __restrict__ wsf, float* __restrict__ out, int nrows)
{
  __shared__ __align__(16) float2 z[RN];      // 64 KB: (pc, tc) interleaved, swizzled
  __shared__ __align__(16) float sc[2256];    // corr partials [31][68] + red + covf

  float* red  = &sc[31 * 68];        // 112 slots
  float* covf = &sc[31 * 68 + 112];  // 32 slots

  const int row = blockIdx.x;
  const int tid = threadIdx.x;
  const int wv  = tid >> 6;
  const int ln  = tid & 63;
  const float* __restrict__ prow = preds   + (size_t)row * RN;
  const float* __restrict__ trow = targets + (size_t)row * RN;

  // ---- phase 1: load own 8 contiguous elements, sum + sumsq partials (1 barrier)
  float pr[8], tw[8];
  {
    float4 p0 = ((const float4*)prow)[2*tid], p1 = ((const float4*)prow)[2*tid+1];
    float4 q0 = ((const float4*)trow)[2*tid], q1 = ((const float4*)trow)[2*tid+1];
    pr[0]=p0.x; pr[1]=p0.y; pr[2]=p0.z; pr[3]=p0.w;
    pr[4]=p1.x; pr[5]=p1.y; pr[6]=p1.z; pr[7]=p1.w;
    tw[0]=q0.x; tw[1]=q0.y; tw[2]=q0.z; tw[3]=q0.w;
    tw[4]=q1.x; tw[5]=q1.y; tw[6]=q1.z; tw[7]=q1.w;
  }
  float sp = 0.f, st = 0.f, ssp = 0.f, sst = 0.f;
  #pragma unroll
  for (int e = 0; e < 8; ++e) {
    sp += pr[e]; st += tw[e];
    ssp += pr[e]*pr[e]; sst += tw[e]*tw[e];
  }
  sp = wave_sum63(sp); st = wave_sum63(st);
  ssp = wave_sum63(ssp); sst = wave_sum63(sst);
  if (ln == 63) { red[wv] = sp; red[16+wv] = st; red[32+wv] = ssp; red[48+wv] = sst; }
  __syncthreads();                                   // b1
  float mean_p, mean_t, inv_denom;
  {
    const float4* rf = (const float4*)red;
    float a0=0.f, a1=0.f, a2=0.f, a3=0.f;
    #pragma unroll
    for (int c = 0; c < 4; ++c) {
      float4 x = rf[c], y = rf[4+c], u = rf[8+c], v = rf[12+c];
      a0 += (x.x+x.y)+(x.z+x.w); a1 += (y.x+y.y)+(y.z+y.w);
      a2 += (u.x+u.y)+(u.z+u.w); a3 += (v.x+v.y)+(v.z+v.w);
    }
    mean_p = a0 * (1.0f/RN); mean_t = a1 * (1.0f/RN);
    float dp = a2 - (float)RN * mean_p * mean_p;     // sum (p-mp)^2
    float dt = a3 - (float)RN * mean_t * mean_t;
    inv_denom = rsqrtf((dp + EPSF) * (dt + EPSF));
  }

  // ---- phase 2: center in regs, single AoS write
  float pcr[8], tcr[8];
  #pragma unroll
  for (int e = 0; e < 8; ++e) { pcr[e] = pr[e] - mean_p; tcr[e] = tw[e] - mean_t; }
  #pragma unroll
  for (int c = 0; c < 4; ++c)
    ((float4*)z)[SW4(4*tid + c)] =
        make_float4(pcr[2*c], tcr[2*c], pcr[2*c+1], tcr[2*c+1]);
  __syncthreads();                                   // b2

  // ---- phase 3: 31-shift circular correlation (own 8 elements, windows from LDS)
  // acc[s] = sum_e pc[8t + e + 15 - s] * tc[8t + e]
  {  // group A: s = 0..15, window wA[k] = pc[8t+k], k in [0,22]
    float wA[24];
    #pragma unroll
    for (int e = 0; e < 8; ++e) wA[e] = pcr[e];
    #pragma unroll
    for (int c = 0; c < 8; ++c) {
      float4 v = ((const float4*)z)[SW4((4*tid + 4 + c) & 2047)];
      wA[8 + 2*c] = v.x; wA[9 + 2*c] = v.z;
    }
    float acc[16];
    #pragma unroll
    for (int s = 0; s < 16; ++s) acc[s] = 0.f;
    #pragma unroll
    for (int e = 0; e < 8; ++e)
      #pragma unroll
      for (int s = 0; s < 16; ++s)
        acc[s] += wA[e + 15 - s] * tcr[e];
    #pragma unroll
    for (int s = 0; s < 16; ++s) {
      float a = row_sum15(acc[s]);
      if ((tid & 15) == 15) sc[s * 68 + (tid >> 4)] = a;
    }
  }
  {  // group B: s2 = 0..14 (s = 16+s2), window wB[k] = pc[8t-16+k], k in [1,22]
    float wB[24];
    #pragma unroll
    for (int c = 0; c < 8; ++c) {
      float4 v = ((const float4*)z)[SW4((4*tid - 8 + c) & 2047)];
      wB[2*c] = v.x; wB[2*c + 1] = v.z;
    }
    #pragma unroll
    for (int e = 0; e < 8; ++e) wB[16 + e] = pcr[e];
    float acc[15];
    #pragma unroll
    for (int s = 0; s < 15; ++s) acc[s] = 0.f;
    #pragma unroll
    for (int e = 0; e < 8; ++e)
      #pragma unroll
      for (int s = 0; s < 15; ++s)
        acc[s] += wB[e + 15 - s] * tcr[e];
    #pragma unroll
    for (int s = 0; s < 15; ++s) {
      float a = row_sum15(acc[s]);
      if ((tid & 15) == 15) sc[(16 + s) * 68 + (tid >> 4)] = a;
    }
  }
  __syncthreads();                                   // b3

  // cov finish (wave 0 lanes, overlapped with FFT pass 1 on other waves)
  if (tid < 31) {
    float a = 0.f;
    #pragma unroll
    for (int c = 0; c < 16; ++c) {
      float4 v = ((const float4*)sc)[tid * 17 + c];
      a += (v.x + v.y) + (v.z + v.w);
    }
    covf[tid] = a * inv_denom;
  }
  if (tid == 31) covf[31] = -3.4e38f;

  // ---- FFT of z = pc + i*tc: DIF radices 8,8,8,16 (output digit-reversed)
  fft_pass8<10>(z, tid);                             // S=1024
  __syncthreads();                                   // b4
  if (tid == 0) {                                    // best pearson -> atomic
    const float4* cf = (const float4*)covf;
    float m = -3.4e38f;
    #pragma unroll
    for (int c = 0; c < 8; ++c) {
      float4 v = cf[c];
      m = fmaxf(m, fmaxf(fmaxf(v.x, v.y), fmaxf(v.z, v.w)));
    }
    atomicAdd(&wsf[0], fmaxf(m, -1.0f));
  }
  fft_pass8<7>(z, tid);                              // S=128
  __syncthreads();                                   // b5
  fft_pass8<4>(z, tid);                              // S=16
  __syncthreads();                                   // b6
  if (tid < 512) {                                   // final radix-16, j=0, in place
    float xr[16], xi[16];
    #pragma unroll
    for (int c = 0; c < 8; ++c) {
      float4 v = ((const float4*)z)[SW4(8*tid + c)];
      xr[2*c] = v.x; xi[2*c] = v.y; xr[2*c+1] = v.z; xi[2*c+1] = v.w;
    }
    dft16(xr, xi);
    #pragma unroll
    for (int c = 0; c < 8; ++c)
      ((float4*)z)[SW4(8*tid + c)] =
          make_float4(xr[2*c], xi[2*c], xr[2*c+1], xi[2*c+1]);
  }
  __syncthreads();                                   // b7

  // ---- packed-FFT split -> power spectra bins 1..4096 + KL
  const int l = tid & 63, w = tid >> 6;
  float ppv[4], ttv[4];
  float Sp = 0.f, St = 0.f;
  #pragma unroll
  for (int u = 0; u < 4; ++u) {
    int j = ((l & 7) << 9) | (((l >> 3) & 7) << 6) | (w << 2) | u;
    int k = j ? j : 4096;
    float2 A = z[SWA(PPOS(k))];
    float2 B = z[SWA(PPOS(RN - k))];
    float rp = A.x + B.x, ip = A.y - B.y;            // 2*P[k]
    float rt = A.y + B.y, it = B.x - A.x;            // 2*T[k]
    float pp = 0.25f * (rp*rp + ip*ip);
    float tt = 0.25f * (rt*rt + it*it);
    ppv[u] = pp; ttv[u] = tt; Sp += pp; St += tt;
  }
  Sp = wave_sum63(Sp); St = wave_sum63(St);
  if (ln == 63) { red[64 + wv] = Sp; red[80 + wv] = St; }
  __syncthreads();                                   // b8
  float inv_sp, inv_st;
  {
    const float4* rf = (const float4*)red;
    float a0 = 0.f, a1 = 0.f;
    #pragma unroll
    for (int c = 0; c < 4; ++c) {
      float4 x = rf[16 + c], y = rf[20 + c];
      a0 += (x.x+x.y)+(x.z+x.w); a1 += (y.x+y.y)+(y.z+y.w);
    }
    inv_sp = 1.0f / (a0 + EPSF);
    inv_st = 1.0f / (a1 + EPSF);
  }
  float kl = 0.f;
  #pragma unroll
  for (int u = 0; u < 4; ++u) {
    float qp = ppv[u] * inv_sp;
    float qt = ttv[u] * inv_st;
    kl += qt * (__log2f(qt + EPSF) - __log2f(qp + EPSF));
  }
  kl *= 0.6931471805599453f;
  kl = wave_sum63(kl);
  if (ln == 63) red[96 + wv] = kl;
  __syncthreads();                                   // b9

  // ---- per-block atomics + completion-counter finalize (single-kernel)
  if (tid == 0) {
    const float4* rf = (const float4*)red;
    float a = 0.f;
    #pragma unroll
    for (int c = 0; c < 4; ++c) {
      float4 x = rf[24 + c];
      a += (x.x + x.y) + (x.z + x.w);
    }
    atomicAdd(&wsf[1], a);
    __threadfence();
    unsigned old = atomicAdd((unsigned*)&wsf[2], 1u);
    if (old == (unsigned)(nrows - 1)) {              // last block finalizes
      float sb = atomicAdd(&wsf[0], 0.0f);
      float sk = atomicAdd(&wsf[1], 0.0f);
      float time_loss = 1.0f - sb / (float)nrows;
      float freq_loss = sk / (float)nrows;
      out[0] = 0.5f * time_loss + 0.5f * freq_loss;  // FREQ_WEIGHT = 0.5
    }
  }
}

extern "C" void kernel_launch(void* const* d_in, const int* in_sizes, int n_in,
                              void* d_out, int out_size, void* d_ws, size_t ws_size,
                              hipStream_t stream) {
  const float* preds   = (const float*)d_in[0];
  const float* targets = (const float*)d_in[1];
  float* out = (float*)d_out;
  float* ws  = (float*)d_ws;   // ws[0]=sum best_pearson, ws[1]=sum kl, ws[2]=counter
  int nrows = in_sizes[0] / RN;
  hipMemsetAsync(d_ws, 0, 16, stream);
  hipLaunchKernelGGL(hybrid_row_kernel, dim3(nrows), dim3(BLK), 0, stream,
                     preds, targets, ws, out, nrows);
}

// Round 6
// 236.514 us; speedup vs baseline: 1.0353x; 1.0353x over previous
//
#include <hip/hip_runtime.h>

#define RN    8192
#define BLK   512         // threads per block (8 waves), EPT = 16
#define EPSF  1e-8f

// LDS: z[8192] float2 AoS (p,t). Swizzle on float4-index: XOR bits 0-2 with bits 4-6.
__device__ __forceinline__ int SW4(int a) { return a ^ ((a >> 4) & 7); }
// 3-digit octal reverse (freq residue owned by thread t after DIF 8,8,8,16)
__device__ __forceinline__ int REV8(int t) { return ((t & 7) << 6) | (t & 56) | (t >> 6); }

// ---- DPP reductions (VALU pipe only) ----
template<int CTRL, int RMASK>
__device__ __forceinline__ float dpp_add_f(float x) {
  int v = __builtin_amdgcn_update_dpp(0, __float_as_int(x), CTRL, RMASK, 0xf, true);
  return x + __int_as_float(v);
}
__device__ __forceinline__ float wave_sum63(float x) {   // total in lane 63
  x = dpp_add_f<0x111, 0xf>(x);
  x = dpp_add_f<0x112, 0xf>(x);
  x = dpp_add_f<0x114, 0xf>(x);
  x = dpp_add_f<0x118, 0xf>(x);
  x = dpp_add_f<0x142, 0xa>(x);   // row_bcast:15
  x = dpp_add_f<0x143, 0xc>(x);   // row_bcast:31
  return x;
}
__device__ __forceinline__ float row_sum15(float x) {    // 16-group total in lane 15
  x = dpp_add_f<0x111, 0xf>(x);
  x = dpp_add_f<0x112, 0xf>(x);
  x = dpp_add_f<0x114, 0xf>(x);
  x = dpp_add_f<0x118, 0xf>(x);
  return x;
}

// ---- 8-point DFT in registers (forward, natural-order output) ----
__device__ __forceinline__ void dft8(float yr[8], float yi[8]) {
  const float C = 0.7071067811865476f;
  float ar, ai;
  float u0r = yr[0] + yr[4], u0i = yi[0] + yi[4];
  float v0r = yr[0] - yr[4], v0i = yi[0] - yi[4];
  float u1r = yr[1] + yr[5], u1i = yi[1] + yi[5];
  ar = yr[1] - yr[5]; ai = yi[1] - yi[5];
  float v1r = C * (ar + ai), v1i = C * (ai - ar);
  float u2r = yr[2] + yr[6], u2i = yi[2] + yi[6];
  ar = yr[2] - yr[6]; ai = yi[2] - yi[6];
  float v2r = ai, v2i = -ar;
  float u3r = yr[3] + yr[7], u3i = yi[3] + yi[7];
  ar = yr[3] - yr[7]; ai = yi[3] - yi[7];
  float v3r = C * (ai - ar), v3i = -C * (ar + ai);
  float t0r = u0r + u2r, t0i = u0i + u2i;
  float t1r = u1r + u3r, t1i = u1i + u3i;
  float t2r = u0r - u2r, t2i = u0i - u2i;
  float t3r = u1r - u3r, t3i = u1i - u3i;
  yr[0] = t0r + t1r; yi[0] = t0i + t1i;
  yr[4] = t0r - t1r; yi[4] = t0i - t1i;
  yr[2] = t2r + t3i; yi[2] = t2i - t3r;
  yr[6] = t2r - t3i; yi[6] = t2i + t3r;
  t0r = v0r + v2r; t0i = v0i + v2i;
  t1r = v1r + v3r; t1i = v1i + v3i;
  t2r = v0r - v2r; t2i = v0i - v2i;
  t3r = v1r - v3r; t3i = v1i - v3i;
  yr[1] = t0r + t1r; yi[1] = t0i + t1i;
  yr[5] = t0r - t1r; yi[5] = t0i - t1i;
  yr[3] = t2r + t3i; yi[3] = t2i - t3r;
  yr[7] = t2r - t3i; yi[7] = t2i + t3r;
}

__device__ __forceinline__ void dft16(float zr[16], float zi[16]) {
  float er[8], ei[8], odr[8], odi[8];
  #pragma unroll
  for (int m = 0; m < 8; ++m) {
    er[m] = zr[2*m];    ei[m] = zi[2*m];
    odr[m] = zr[2*m+1]; odi[m] = zi[2*m+1];
  }
  dft8(er, ei); dft8(odr, odi);
  const float c1 = 0.9238795325112867f, s1 = 0.3826834323650898f;
  const float C  = 0.7071067811865476f;
  const float WR[8] = {1.f,  c1,  C,  s1, 0.f, -s1, -C, -c1};
  const float WI[8] = {0.f, -s1, -C, -c1, -1.f, -c1, -C, -s1};
  #pragma unroll
  for (int q = 0; q < 8; ++q) {
    float tr = odr[q]*WR[q] - odi[q]*WI[q];
    float ti = odr[q]*WI[q] + odi[q]*WR[q];
    zr[q]     = er[q] + tr; zi[q]     = ei[q] + ti;
    zr[q + 8] = er[q] - tr; zi[q + 8] = ei[q] - ti;
  }
}

// build w^2..w^7 from w^1 by squaring tree (depth 3, no serial chain)
__device__ __forceinline__ void twtree(float wr[8], float wi[8]) {
  wr[2] = wr[1]*wr[1] - wi[1]*wi[1]; wi[2] = 2.f*wr[1]*wi[1];
  wr[3] = wr[2]*wr[1] - wi[2]*wi[1]; wi[3] = wr[2]*wi[1] + wi[2]*wr[1];
  wr[4] = wr[2]*wr[2] - wi[2]*wi[2]; wi[4] = 2.f*wr[2]*wi[2];
  wr[5] = wr[3]*wr[2] - wi[3]*wi[2]; wi[5] = wr[3]*wi[2] + wi[3]*wr[2];
  wr[6] = wr[3]*wr[3] - wi[3]*wi[3]; wi[6] = 2.f*wr[3]*wi[3];
  wr[7] = wr[4]*wr[3] - wi[4]*wi[3]; wi[7] = wr[4]*wi[3] + wi[4]*wr[3];
}

// One DIF radix-8 pass; thread handles butterflies j=2t (A) and j=2t+1 (B).
// Element m of both butterflies shares one float4 slot -> 8 b128 r + 8 b128 w.
template<int LOG2S>
__device__ __forceinline__ void fft_pass8(float2* z, int t) {
  const int S = 1 << LOG2S;
  const int g = 2 * t;
  const int j = g & (S - 1);                      // even
  const int f4b = (((g >> LOG2S) << (LOG2S + 3)) + j) >> 1;
  float ar[8], ai[8], br[8], bi[8];
  #pragma unroll
  for (int m = 0; m < 8; ++m) {
    float4 v = ((const float4*)z)[SW4(f4b + m * (S >> 1))];
    ar[m] = v.x; ai[m] = v.y; br[m] = v.z; bi[m] = v.w;
  }
  dft8(ar, ai); dft8(br, bi);
  const float ang = -3.14159265358979323846f / (4.0f * (float)S);
  float war[8], wai[8], wbr[8], wbi[8];
  __sincosf(ang * (float)j,       &wai[1], &war[1]);
  __sincosf(ang * (float)(j + 1), &wbi[1], &wbr[1]);
  twtree(war, wai); twtree(wbr, wbi);
  #pragma unroll
  for (int q = 1; q < 8; ++q) {
    float tr = ar[q]*war[q] - ai[q]*wai[q];
    ai[q] = ar[q]*wai[q] + ai[q]*war[q]; ar[q] = tr;
    float ur = br[q]*wbr[q] - bi[q]*wbi[q];
    bi[q] = br[q]*wbi[q] + bi[q]*wbr[q]; br[q] = ur;
  }
  #pragma unroll
  for (int m = 0; m < 8; ++m)
    ((float4*)z)[SW4(f4b + m * (S >> 1))] = make_float4(ar[m], ai[m], br[m], bi[m]);
}

__global__ __launch_bounds__(BLK, 4) void hybrid_row_kernel(
    const float* __restrict__ preds, const float* __restrict__ targets,
    float* __restrict__ wsf, float* __restrict__ out, int nrows)
{
  __shared__ __align__(16) float2 z[RN];       // 64 KB raw (p,t) AoS, swizzled
  __shared__ __align__(16) float sc[31 * 36 + 96];  // cov partials [31][36] + red[96]

  float* red = &sc[31 * 36];
  // red layout: [0,8) sp | [8,16) st | [16,24) ssp | [24,32) sst
  //             [32,40) Sp | [40,48) St | [48,56) kl | [64,95) cov totals

  const int tid = threadIdx.x;
  const int wv  = tid >> 6;
  const int ln  = tid & 63;
  const float* __restrict__ prow = preds   + (size_t)blockIdx.x * RN;
  const float* __restrict__ trow = targets + (size_t)blockIdx.x * RN;

  // ---- phase 1: load own 16 contiguous elements (raw), stats partials, z write
  float pn[16], tn[16];
  #pragma unroll
  for (int c = 0; c < 4; ++c) {
    float4 p = ((const float4*)prow)[4*tid + c];
    float4 q = ((const float4*)trow)[4*tid + c];
    pn[4*c+0] = p.x; pn[4*c+1] = p.y; pn[4*c+2] = p.z; pn[4*c+3] = p.w;
    tn[4*c+0] = q.x; tn[4*c+1] = q.y; tn[4*c+2] = q.z; tn[4*c+3] = q.w;
  }
  {
    float sp = 0.f, st = 0.f, ssp = 0.f, sst = 0.f;
    #pragma unroll
    for (int e = 0; e < 16; ++e) {
      sp += pn[e]; st += tn[e];
      ssp += pn[e]*pn[e]; sst += tn[e]*tn[e];
    }
    sp = wave_sum63(sp); st = wave_sum63(st);
    ssp = wave_sum63(ssp); sst = wave_sum63(sst);
    if (ln == 63) { red[wv] = sp; red[8+wv] = st; red[16+wv] = ssp; red[24+wv] = sst; }
  }
  #pragma unroll
  for (int c = 0; c < 8; ++c)
    ((float4*)z)[SW4(8*tid + c)] =
        make_float4(pn[2*c], tn[2*c], pn[2*c+1], tn[2*c+1]);
  __syncthreads();                                   // b1

  // ---- phase 2: 31-shift circular correlation on RAW data, one shared window
  // A (sh=s-15, s in [0,16)):  accA[s] = sum_e p[16t+e+15-s] * t_own[e]
  // B (sh=s2+1, s2 in [0,15)): accB[s2] = sum_e p_own[e] * t[16t+e+1+s2]
  // Both windows = elements [16t, 16t+31) of (p,t): chunks c in [0,16); c<8 from regs.
  {
    float accA[16], accB[15];
    #pragma unroll
    for (int s = 0; s < 16; ++s) accA[s] = 0.f;
    #pragma unroll
    for (int s = 0; s < 15; ++s) accB[s] = 0.f;
    #pragma unroll
    for (int c = 0; c < 16; ++c) {
      float p0, t0, p1, t1;
      if (c < 8) { p0 = pn[2*c]; t0 = tn[2*c]; p1 = pn[2*c+1]; t1 = tn[2*c+1]; }
      else {
        float4 v = ((const float4*)z)[SW4((8*tid + c) & 4095)];
        p0 = v.x; t0 = v.y; p1 = v.z; t1 = v.w;
      }
      #pragma unroll
      for (int d = 0; d < 2; ++d) {
        const int w = 2*c + d;
        const float pv = d ? p1 : p0;
        const float tv = d ? t1 : t0;
        #pragma unroll
        for (int s = 0; s < 16; ++s) {               // e = w-15+s
          const int e = w - 15 + s;
          if (e >= 0 && e < 16) accA[s] += pv * tn[e];
        }
        #pragma unroll
        for (int s2 = 0; s2 < 15; ++s2) {            // e = w-1-s2
          const int e = w - 1 - s2;
          if (e >= 0 && e < 16) accB[s2] += tv * pn[e];
        }
      }
    }
    #pragma unroll
    for (int s = 0; s < 16; ++s) {
      float a = row_sum15(accA[s]);
      if ((tid & 15) == 15) sc[s * 36 + (tid >> 4)] = a;
    }
    #pragma unroll
    for (int s2 = 0; s2 < 15; ++s2) {
      float a = row_sum15(accB[s2]);
      if ((tid & 15) == 15) sc[(16 + s2) * 36 + (tid >> 4)] = a;
    }
  }
  __syncthreads();                                   // b2

  // ---- FFT of z = p + i*t: DIF radices 8,8,8,16 (digit-reversed output)
  fft_pass8<10>(z, tid);                             // S=1024
  __syncthreads();                                   // b3
  fft_pass8<7>(z, tid);                              // S=128
  __syncthreads();                                   // b4
  fft_pass8<4>(z, tid);                              // S=16
  __syncthreads();                                   // b5
  float xr[16], xi[16];                              // final radix-16 (j=0), own block
  #pragma unroll
  for (int c = 0; c < 8; ++c) {
    float4 v = ((const float4*)z)[SW4(8*tid + c)];
    xr[2*c] = v.x; xi[2*c] = v.y; xr[2*c+1] = v.z; xi[2*c+1] = v.w;
  }
  dft16(xr, xi);
  #pragma unroll
  for (int c = 0; c < 8; ++c)
    ((float4*)z)[SW4(8*tid + c)] =
        make_float4(xr[2*c], xi[2*c], xr[2*c+1], xi[2*c+1]);
  __syncthreads();                                   // b6

  // ---- spectrum split: own freqs k = r + 512*u (r = REV8(t)); partner holds N-k.
  // Own Z[k] stays in regs; read only partner's upper half-block (4 b128).
  float ppv[8], ttv[8];
  {
    const int r  = REV8(tid);
    const int t2 = REV8((512 - r) & 511);
    float prr[8], pri[8];
    #pragma unroll
    for (int c = 0; c < 4; ++c) {
      float4 v = ((const float4*)z)[SW4(8*t2 + 4 + c)];
      prr[2*c] = v.x; pri[2*c] = v.y; prr[2*c+1] = v.z; pri[2*c+1] = v.w;
    }
    const int ofs = (r == 0) ? 1 : 0;                // r=0 thread covers k=512..4096
    float Sp = 0.f, St = 0.f;
    #pragma unroll
    for (int u = 0; u < 8; ++u) {
      float Ar = xr[u + ofs], Ai = xi[u + ofs];      // Z[k]
      float Br = prr[7 - u],  Bi = pri[7 - u];       // Z[N-k]
      float rp = Ar + Br, ip = Ai - Bi;              // 2*P[k]
      float rt = Ai + Bi, it = Br - Ar;              // 2*T[k]
      float pp = 0.25f * (rp*rp + ip*ip);
      float tt = 0.25f * (rt*rt + it*it);
      ppv[u] = pp; ttv[u] = tt; Sp += pp; St += tt;
    }
    Sp = wave_sum63(Sp); St = wave_sum63(St);
    if (ln == 63) { red[32 + wv] = Sp; red[40 + wv] = St; }
  }
  __syncthreads();                                   // b7

  // ---- KL terms (all threads) + cov row totals (threads 0..30)
  {
    float a0 = 0.f, a1 = 0.f;
    #pragma unroll
    for (int w = 0; w < 8; ++w) { a0 += red[32 + w]; a1 += red[40 + w]; }
    const float inv_sp = 1.0f / (a0 + EPSF);
    const float inv_st = 1.0f / (a1 + EPSF);
    float kl = 0.f;
    #pragma unroll
    for (int u = 0; u < 8; ++u) {
      float qp = ppv[u] * inv_sp;
      float qt = ttv[u] * inv_st;
      kl += qt * (__log2f(qt + EPSF) - __log2f(qp + EPSF));
    }
    kl = wave_sum63(kl * 0.6931471805599453f);
    if (ln == 63) red[48 + wv] = kl;
  }
  if (tid < 31) {
    float a = 0.f;
    #pragma unroll
    for (int c = 0; c < 8; ++c) {
      float4 v = ((const float4*)sc)[tid * 9 + c];   // 32 partials of shift tid
      a += (v.x + v.y) + (v.z + v.w);
    }
    red[64 + tid] = a;                               // raw cov total
  }
  __syncthreads();                                   // b8

  // ---- thread 0: finalize row, one atomic + completion counter
  if (tid == 0) {
    float sp = 0.f, st = 0.f, ssp = 0.f, sst = 0.f, kl = 0.f;
    #pragma unroll
    for (int w = 0; w < 8; ++w) {
      sp += red[w]; st += red[8+w]; ssp += red[16+w]; sst += red[24+w];
      kl += red[48+w];
    }
    const float mp = sp * (1.0f/RN), mt = st * (1.0f/RN);
    const float dp = ssp - (float)RN * mp * mp;
    const float dt = sst - (float)RN * mt * mt;
    const float inv_denom = rsqrtf((dp + EPSF) * (dt + EPSF));
    float m = red[64];
    #pragma unroll
    for (int s = 1; s < 31; ++s) m = fmaxf(m, red[64 + s]);
    const float best = fmaxf((m - (float)RN * mp * mt) * inv_denom, -1.0f);
    atomicAdd(&wsf[0], 0.5f * (kl - best));          // loss contribution
    __threadfence();
    unsigned old = atomicAdd((unsigned*)&wsf[1], 1u);
    if (old == (unsigned)(nrows - 1)) {
      float acc = atomicAdd(&wsf[0], 0.0f);
      out[0] = 0.5f + acc / (float)nrows;            // 0.5*(1-mean_best)+0.5*mean_kl
    }
  }
}

extern "C" void kernel_launch(void* const* d_in, const int* in_sizes, int n_in,
                              void* d_out, int out_size, void* d_ws, size_t ws_size,
                              hipStream_t stream) {
  const float* preds   = (const float*)d_in[0];
  const float* targets = (const float*)d_in[1];
  float* out = (float*)d_out;
  float* ws  = (float*)d_ws;   // ws[0] = loss accumulator, ws[1] = block counter
  int nrows = in_sizes[0] / RN;
  hipMemsetAsync(d_ws, 0, 16, stream);
  hipLaunchKernelGGL(hybrid_row_kernel, dim3(nrows), dim3(BLK), 0, stream,
                     preds, targets, ws, out, nrows);
}